// Round 4
// baseline (303.339 us; speedup 1.0000x reference)
//
#include <hip/hip_runtime.h>

// YOLO loss: S=14, B=2, C=20, N_CH=30, batch=4096
// pred, target: (4096, 14, 14, 30) float32. Output: scalar float32.
//
// R3 theory: memory LANE-instructions (VMEM+DS ~1 lane/cyc/CU) are the
// limiter, not HBM BW and not atomics. Minimize lane-ops: 2 cells/thread,
// 15 float4 loads per tensor per thread (15 lane-ops/cell vs 60 in R2).
// No LDS staging, no barriers, continuous MLP.

#define SDIM 14
#define NCH  30
#define BATCH 4096
#define NCELLS (BATCH * SDIM * SDIM)     // 802816
#define L_COORD 5.0f
#define L_NOOBJ 0.5f

#define THREADS 256
#define CELLS_PER_THREAD 2
#define CELLS_PER_BLOCK (THREADS * CELLS_PER_THREAD)   // 512
#define NBLOCKS (NCELLS / CELLS_PER_BLOCK)             // 1568, exact

__device__ __forceinline__ float cell_loss(const float* pv, const float* tv)
{
    const float invS = 1.0f / (float)SDIM;
    float m  = (tv[4] > 0.0f) ? 1.0f : 0.0f;
    float nm = 1.0f - m;

    // target box 0 -> xyxy
    float tcx = tv[0] * invS, tcy = tv[1] * invS;
    float tw  = tv[2],        th  = tv[3];
    float tx1 = tcx - 0.5f * tw, ty1 = tcy - 0.5f * th;
    float tx2 = tcx + 0.5f * tw, ty2 = tcy + 0.5f * th;
    float ta  = (tx2 - tx1) * (ty2 - ty1);

    float iou[2];
    #pragma unroll
    for (int b = 0; b < 2; ++b) {
        float cx = pv[5*b + 0] * invS, cy = pv[5*b + 1] * invS;
        float w  = pv[5*b + 2],        h  = pv[5*b + 3];
        float x1 = cx - 0.5f * w, y1 = cy - 0.5f * h;
        float x2 = cx + 0.5f * w, y2 = cy + 0.5f * h;
        float lx = fmaxf(x1, tx1), ly = fmaxf(y1, ty1);
        float rx = fminf(x2, tx2), ry = fminf(y2, ty2);
        float iw = fmaxf(rx - lx, 0.0f);
        float ih = fmaxf(ry - ly, 0.0f);
        float inter = iw * ih;
        float pa = (x2 - x1) * (y2 - y1);
        iou[b] = inter / (pa + ta - inter);
    }

    // argmax (first-wins on ties, matching jnp.argmax)
    int   idx     = (iou[1] > iou[0]) ? 1 : 0;
    float max_iou = idx ? iou[1] : iou[0];
    int   o       = 5 * idx;

    float dxy = (pv[o+0] - tv[o+0]) * (pv[o+0] - tv[o+0])
              + (pv[o+1] - tv[o+1]) * (pv[o+1] - tv[o+1]);
    float sw  = sqrtf(pv[o+2]) - sqrtf(tv[o+2]);
    float sh  = sqrtf(pv[o+3]) - sqrtf(tv[o+3]);
    float dwh = sw * sw + sh * sh;
    float dob = (pv[o+4] - max_iou) * (pv[o+4] - max_iou);

    float dcls = 0.0f;
    #pragma unroll
    for (int c = 10; c < NCH; ++c) {
        float d = pv[c] - tv[c];
        dcls += d * d;
    }

    float d4 = pv[4] - tv[4];
    float d9 = pv[9] - tv[9];
    float dnoobj = d4 * d4 + d9 * d9;

    return m * (L_COORD * (dxy + dwh) + dob + dcls) + nm * L_NOOBJ * dnoobj;
}

__global__ __launch_bounds__(256) void yolo_loss_stage1(
    const float* __restrict__ pred,
    const float* __restrict__ tgt,
    float* __restrict__ partial)
{
    const int tid = threadIdx.x;
    // Thread owns 2 adjacent cells: 240 B per tensor = 15 float4 (16B-aligned).
    const size_t cell0 = (size_t)blockIdx.x * CELLS_PER_BLOCK + (size_t)tid * 2;

    const float4* p4 = (const float4*)(pred + cell0 * NCH);
    const float4* t4 = (const float4*)(tgt  + cell0 * NCH);

    float pv[60], tv[60];
    #pragma unroll
    for (int j = 0; j < 15; ++j) {
        float4 a = p4[j];
        pv[4*j+0] = a.x; pv[4*j+1] = a.y; pv[4*j+2] = a.z; pv[4*j+3] = a.w;
    }
    #pragma unroll
    for (int j = 0; j < 15; ++j) {
        float4 b = t4[j];
        tv[4*j+0] = b.x; tv[4*j+1] = b.y; tv[4*j+2] = b.z; tv[4*j+3] = b.w;
    }

    float loss = cell_loss(pv, tv) + cell_loss(pv + 30, tv + 30);

    // Reduction: wave shuffle (64) -> LDS -> one partial per block (no atomics)
    #pragma unroll
    for (int off = 32; off > 0; off >>= 1)
        loss += __shfl_down(loss, off, 64);

    __shared__ float wsum[4];
    int lane = tid & 63;
    int wid  = tid >> 6;
    if (lane == 0) wsum[wid] = loss;
    __syncthreads();
    if (tid == 0) {
        partial[blockIdx.x] = wsum[0] + wsum[1] + wsum[2] + wsum[3];
    }
}

__global__ __launch_bounds__(256) void yolo_loss_stage2(
    const float* __restrict__ partial,
    float* __restrict__ out)
{
    const int tid = threadIdx.x;
    float s = 0.0f;
    for (int i = tid; i < NBLOCKS; i += 256) s += partial[i];

    #pragma unroll
    for (int off = 32; off > 0; off >>= 1)
        s += __shfl_down(s, off, 64);

    __shared__ float wsum[4];
    int lane = tid & 63;
    int wid  = tid >> 6;
    if (lane == 0) wsum[wid] = s;
    __syncthreads();
    if (tid == 0) {
        out[0] = (wsum[0] + wsum[1] + wsum[2] + wsum[3]) * (1.0f / (float)BATCH);
    }
}

extern "C" void kernel_launch(void* const* d_in, const int* in_sizes, int n_in,
                              void* d_out, int out_size, void* d_ws, size_t ws_size,
                              hipStream_t stream)
{
    const float* pred = (const float*)d_in[0];
    const float* tgt  = (const float*)d_in[1];
    float* out        = (float*)d_out;
    float* partial    = (float*)d_ws;   // 1568 floats

    hipLaunchKernelGGL(yolo_loss_stage1, dim3(NBLOCKS), dim3(THREADS), 0, stream,
                       pred, tgt, partial);
    hipLaunchKernelGGL(yolo_loss_stage2, dim3(1), dim3(256), 0, stream,
                       partial, out);
}

// Round 5
// 211.861 us; speedup vs baseline: 1.4318x; 1.4318x over previous
//
#include <hip/hip_runtime.h>

// YOLO loss: S=14, B=2, C=20, N_CH=30, batch=4096
// pred, target: (4096, 14, 14, 30) float32. Output: scalar float32.
//
// R5: test the global_load_lds DMA path (the only untried read mechanism).
// 128 threads / 128-cell tile; both tensors async-DMA'd into one 30 KiB LDS
// buffer; single barrier; per-cell math from LDS; two-stage reduction.
// Cross-round evidence: TCP-return loads pin at ~2.35 TB/s regardless of
// pattern/occupancy/barriers (R0 2.39, R2 2.35, R4 2.28).

#define SDIM 14
#define NCH  30
#define BATCH 4096
#define NCELLS (BATCH * SDIM * SDIM)     // 802816
#define L_COORD 5.0f
#define L_NOOBJ 0.5f

#define THREADS 128
#define TILE_CELLS 128
#define NBLOCKS (NCELLS / TILE_CELLS)    // 6272, exact
#define TILE_F4 (TILE_CELLS * NCH / 4)   // 960 float4 per tensor

__device__ __forceinline__ void async_copy16(void* lds_uniform_base,
                                             const float4* gsrc_lane)
{
    // LDS dest is wave-uniform base; HW writes lane L at base + L*16.
    __builtin_amdgcn_global_load_lds(
        (const __attribute__((address_space(1))) void*)gsrc_lane,
        (__attribute__((address_space(3))) void*)lds_uniform_base,
        16, 0, 0);
}

__device__ __forceinline__ float cell_loss(const float* __restrict__ pv,
                                           const float* __restrict__ tv)
{
    const float invS = 1.0f / (float)SDIM;
    float m  = (tv[4] > 0.0f) ? 1.0f : 0.0f;
    float nm = 1.0f - m;

    // target box 0 -> xyxy
    float tcx = tv[0] * invS, tcy = tv[1] * invS;
    float tw  = tv[2],        th  = tv[3];
    float tx1 = tcx - 0.5f * tw, ty1 = tcy - 0.5f * th;
    float tx2 = tcx + 0.5f * tw, ty2 = tcy + 0.5f * th;
    float ta  = (tx2 - tx1) * (ty2 - ty1);

    float iou[2];
    #pragma unroll
    for (int b = 0; b < 2; ++b) {
        float cx = pv[5*b + 0] * invS, cy = pv[5*b + 1] * invS;
        float w  = pv[5*b + 2],        h  = pv[5*b + 3];
        float x1 = cx - 0.5f * w, y1 = cy - 0.5f * h;
        float x2 = cx + 0.5f * w, y2 = cy + 0.5f * h;
        float lx = fmaxf(x1, tx1), ly = fmaxf(y1, ty1);
        float rx = fminf(x2, tx2), ry = fminf(y2, ty2);
        float iw = fmaxf(rx - lx, 0.0f);
        float ih = fmaxf(ry - ly, 0.0f);
        float inter = iw * ih;
        float pa = (x2 - x1) * (y2 - y1);
        iou[b] = inter / (pa + ta - inter);
    }

    // argmax (first-wins on ties, matching jnp.argmax); o is 0 or 5 ->
    // compiler lowers pv[o+k] to cndmask selects (no spillable array).
    int   idx     = (iou[1] > iou[0]) ? 1 : 0;
    float max_iou = idx ? iou[1] : iou[0];
    int   o       = 5 * idx;

    float dxy = (pv[o+0] - tv[o+0]) * (pv[o+0] - tv[o+0])
              + (pv[o+1] - tv[o+1]) * (pv[o+1] - tv[o+1]);
    float sw  = sqrtf(pv[o+2]) - sqrtf(tv[o+2]);
    float sh  = sqrtf(pv[o+3]) - sqrtf(tv[o+3]);
    float dwh = sw * sw + sh * sh;
    float dob = (pv[o+4] - max_iou) * (pv[o+4] - max_iou);

    float dcls = 0.0f;
    #pragma unroll
    for (int c = 10; c < NCH; ++c) {
        float d = pv[c] - tv[c];
        dcls += d * d;
    }

    float d4 = pv[4] - tv[4];
    float d9 = pv[9] - tv[9];
    float dnoobj = d4 * d4 + d9 * d9;

    return m * (L_COORD * (dxy + dwh) + dob + dcls) + nm * L_NOOBJ * dnoobj;
}

__global__ __launch_bounds__(THREADS) void yolo_loss_stage1(
    const float* __restrict__ pred,
    const float* __restrict__ tgt,
    float* __restrict__ partial)
{
    __shared__ float tile[2 * TILE_CELLS * NCH];   // pred [0,3840), tgt [3840,7680)

    const int tid  = threadIdx.x;
    const int w    = tid >> 6;    // wave id (0/1), wave-uniform
    const int lane = tid & 63;
    const size_t cell0 = (size_t)blockIdx.x * TILE_CELLS;

    const float4* gp = (const float4*)(pred + cell0 * NCH);
    const float4* gt = (const float4*)(tgt  + cell0 * NCH);
    float4* l4 = (float4*)tile;   // [0,960) pred, [960,1920) tgt

    // Async DMA staging: 960 float4 per tensor; per call a wave moves
    // 64 x 16 B = 1 KiB. j=0..6 covers 896; the last 64 go to wave 0 only.
    #pragma unroll
    for (int j = 0; j < 7; ++j) {
        int idx = j * 128 + w * 64;             // wave-uniform base
        async_copy16(&l4[idx],       gp + idx + lane);
        async_copy16(&l4[960 + idx], gt + idx + lane);
    }
    if (w == 0) {
        async_copy16(&l4[896],       gp + 896 + lane);
        async_copy16(&l4[960 + 896], gt + 896 + lane);
    }
    __syncthreads();   // drains vmcnt (global_load_lds) before LDS reads

    // Per-cell math straight from LDS (thread tid owns cell tid).
    float pv[NCH], tv[NCH];
    {
        const float2* lp = (const float2*)(tile + tid * NCH);
        const float2* lt = (const float2*)(tile + TILE_CELLS * NCH + tid * NCH);
        #pragma unroll
        for (int i = 0; i < NCH / 2; ++i) {
            float2 a = lp[i]; pv[2*i] = a.x; pv[2*i+1] = a.y;
            float2 b = lt[i]; tv[2*i] = b.x; tv[2*i+1] = b.y;
        }
    }

    float loss = cell_loss(pv, tv);

    // Reduction: wave shuffle (64) -> LDS -> one partial per block
    #pragma unroll
    for (int off = 32; off > 0; off >>= 1)
        loss += __shfl_down(loss, off, 64);

    __shared__ float wsum[2];
    if (lane == 0) wsum[w] = loss;
    __syncthreads();
    if (tid == 0) partial[blockIdx.x] = wsum[0] + wsum[1];
}

__global__ __launch_bounds__(256) void yolo_loss_stage2(
    const float* __restrict__ partial,
    float* __restrict__ out)
{
    const int tid = threadIdx.x;
    float s = 0.0f;
    for (int i = tid; i < NBLOCKS; i += 256) s += partial[i];

    #pragma unroll
    for (int off = 32; off > 0; off >>= 1)
        s += __shfl_down(s, off, 64);

    __shared__ float wsum[4];
    int lane = tid & 63;
    int wid  = tid >> 6;
    if (lane == 0) wsum[wid] = s;
    __syncthreads();
    if (tid == 0) {
        out[0] = (wsum[0] + wsum[1] + wsum[2] + wsum[3]) * (1.0f / (float)BATCH);
    }
}

extern "C" void kernel_launch(void* const* d_in, const int* in_sizes, int n_in,
                              void* d_out, int out_size, void* d_ws, size_t ws_size,
                              hipStream_t stream)
{
    const float* pred = (const float*)d_in[0];
    const float* tgt  = (const float*)d_in[1];
    float* out        = (float*)d_out;
    float* partial    = (float*)d_ws;   // 6272 floats = 25 KB

    hipLaunchKernelGGL(yolo_loss_stage1, dim3(NBLOCKS), dim3(THREADS), 0, stream,
                       pred, tgt, partial);
    hipLaunchKernelGGL(yolo_loss_stage2, dim3(1), dim3(256), 0, stream,
                       partial, out);
}